// Round 3
// baseline (19008.495 us; speedup 1.0000x reference)
//
#include <hip/hip_runtime.h>

typedef unsigned short ushort_t;

static constexpr int BATCH = 1024;
static constexpr int TT = 128;   // T
static constexpr int NN = 128;   // N
static constexpr int MM = 256;   // M == P

__device__ __forceinline__ float bf2f(ushort_t u) {
    union { unsigned int i; float f; } v;
    v.i = ((unsigned int)u) << 16;
    return v.f;
}
__device__ __forceinline__ ushort_t f2bf(float f) {
    union { unsigned int i; float f; } v;
    v.f = f;
    unsigned int i = v.i;
    return (ushort_t)((i + 0x7FFFu + ((i >> 16) & 1u)) >> 16);
}
__device__ __forceinline__ float tanh_fast(float x) {
    x = fminf(9.0f, fmaxf(-9.0f, x));
    float e = __expf(2.0f * x);
    return 1.0f - __fdividef(2.0f, e + 1.0f);
}
__device__ __forceinline__ float sig_fast(float x) {
    x = fminf(30.0f, fmaxf(-30.0f, x));
    return __fdividef(1.0f, 1.0f + __expf(-x));
}

// ---------------------------------------------------------------------------
// Generic tiled GEMM (verified R1) — only for the two one-time precomputes.
// ---------------------------------------------------------------------------
template<bool WBF16, bool TRANSW, bool CBF16, bool RELU>
__global__ __launch_bounds__(256) void gemm_k(
    const float* __restrict__ A1, int lda1, long sA1z, int K1,
    const float* __restrict__ A2, int lda2, int K2,
    const void* __restrict__ W1v, int ldw1, long sW1z,
    const void* __restrict__ W2v, int ldw2,
    const float* __restrict__ bias1,
    void* __restrict__ Cv, int ldc, long sCz)
{
    __shared__ float As[32][68];
    __shared__ float Ws[32][68];
    const int tid = threadIdx.x;
    const int z = blockIdx.z;
    const int m0 = blockIdx.y * 64;
    const int g0 = blockIdx.x * 64;
    const int tm = tid & 15, tn = tid >> 4;
    float acc[4][4];
#pragma unroll
    for (int i = 0; i < 4; ++i)
#pragma unroll
        for (int j = 0; j < 4; ++j) acc[i][j] = 0.0f;

    for (int phase = 0; phase < 2; ++phase) {
        const float* A = (phase == 0) ? (A1 + (long)z * sA1z) : A2;
        const int lda = (phase == 0) ? lda1 : lda2;
        const int K = (phase == 0) ? K1 : K2;
        const int ldw = (phase == 0) ? ldw1 : ldw2;
        const void* Wv = (phase == 0) ? W1v : W2v;
        const long woff = (phase == 0) ? (long)z * sW1z : 0;
        if (A == nullptr || Wv == nullptr || K <= 0) continue;

        for (int k0 = 0; k0 < K; k0 += 32) {
            const int rem = K - k0;
            {
                const int tr0 = tid >> 3;
                const int tk = (tid & 7) * 4;
#pragma unroll
                for (int pass = 0; pass < 2; ++pass) {
                    const int m = tr0 + pass * 32;
                    const float* p = A + (long)(m0 + m) * lda + k0 + tk;
#pragma unroll
                    for (int j = 0; j < 4; ++j) {
                        float v = 0.0f;
                        if (tk + j < rem) v = p[j];
                        As[tk + j][m] = v;
                    }
                }
            }
            if constexpr (TRANSW) {
                const float* W = (const float*)Wv + woff;
                const int gq = (tid & 15) * 4;
                const int kr = tid >> 4;
#pragma unroll
                for (int pass = 0; pass < 2; ++pass) {
                    const int k = kr + pass * 16;
                    const float* p = W + (long)(k0 + k) * ldw + g0 + gq;
                    const bool ok = (k < rem);
#pragma unroll
                    for (int j = 0; j < 4; ++j) {
                        float v = 0.0f;
                        if (ok) v = p[j];
                        Ws[k][gq + j] = v;
                    }
                }
            } else if constexpr (WBF16) {
                const ushort_t* W = (const ushort_t*)Wv + woff;
                const int g = tid >> 2;
                const int tk = (tid & 3) * 8;
                const ushort_t* p = W + (long)(g0 + g) * ldw + k0 + tk;
#pragma unroll
                for (int j = 0; j < 8; ++j) {
                    float v = 0.0f;
                    if (tk + j < rem) v = bf2f(p[j]);
                    Ws[tk + j][g] = v;
                }
            } else {
                const float* W = (const float*)Wv + woff;
                const int tr0 = tid >> 3;
                const int tk = (tid & 7) * 4;
#pragma unroll
                for (int pass = 0; pass < 2; ++pass) {
                    const int g = tr0 + pass * 32;
                    const float* p = W + (long)(g0 + g) * ldw + k0 + tk;
#pragma unroll
                    for (int j = 0; j < 4; ++j) {
                        float v = 0.0f;
                        if (tk + j < rem) v = p[j];
                        Ws[tk + j][g] = v;
                    }
                }
            }
            __syncthreads();
#pragma unroll
            for (int kk = 0; kk < 32; ++kk) {
                const float4 av = *(const float4*)&As[kk][tm * 4];
                const float4 bv = *(const float4*)&Ws[kk][tn * 4];
                const float a[4] = {av.x, av.y, av.z, av.w};
                const float b[4] = {bv.x, bv.y, bv.z, bv.w};
#pragma unroll
                for (int i = 0; i < 4; ++i)
#pragma unroll
                    for (int j = 0; j < 4; ++j)
                        acc[i][j] = fmaf(a[i], b[j], acc[i][j]);
            }
            __syncthreads();
        }
    }
#pragma unroll
    for (int i = 0; i < 4; ++i) {
        const long m = m0 + tm * 4 + i;
#pragma unroll
        for (int j = 0; j < 4; ++j) {
            const int g = g0 + tn * 4 + j;
            float v = acc[i][j];
            if (bias1) v += bias1[g];
            if (RELU) v = fmaxf(v, 0.0f);
            if constexpr (CBF16)
                ((ushort_t*)Cv)[(long)z * sCz + m * ldc + g] = f2bf(v);
            else
                ((float*)Cv)[(long)z * sCz + m * ldc + g] = v;
        }
    }
}

// ---------------------------------------------------------------------------
// Weight prep
// ---------------------------------------------------------------------------
__global__ void prep_encw_k(const float* __restrict__ Wih, const float* __restrict__ Whh,
                            float* __restrict__ dst) {
    int i = blockIdx.x * 256 + threadIdx.x;
    if (i >= 384 * 1024) return;
    int k = i >> 10, col = i & 1023, u = col >> 2, q = col & 3, g = q * 256 + u;
    dst[i] = (k < 128) ? Wih[g * 128 + k] : Whh[g * 256 + (k - 128)];
}

__global__ void prep_decw_k(const float* __restrict__ Wih, const float* __restrict__ Whh,
                            float* __restrict__ dst) {
    int i = blockIdx.x * 256 + threadIdx.x;
    if (i >= 257 * 1024) return;
    int k = i >> 10, col = i & 1023, u = col >> 2, q = col & 3, g = q * 256 + u;
    dst[i] = (k == 0) ? Wih[g] : Whh[g * 256 + (k - 1)];
}

__global__ void transpose_k(const float* __restrict__ src, float* __restrict__ dst,
                            int R, int C) {
    int i = blockIdx.x * 256 + threadIdx.x;
    if (i < R * C) { int r = i / C, c = i - r * C; dst[c * R + r] = src[i]; }
}

// ---------------------------------------------------------------------------
// Persistent encoder: 256 blocks x 512 threads (8 waves); block owns 4 batch
// rows. Every phase is split across the extra threads; LDS partial combines.
// ---------------------------------------------------------------------------
__global__ __launch_bounds__(512) void enc_persist(
    const float* __restrict__ enc_data,   // [1024][128][128]
    const ushort_t* __restrict__ D,       // [1024][128][128] bf16
    const float* __restrict__ WeT,        // [512][128]
    const float* __restrict__ ve,         // [128]
    const float* __restrict__ WencT,      // [384][1024]
    const float* __restrict__ bih, const float* __restrict__ bhh,
    ushort_t* __restrict__ Hbf)           // [1024][128][256] bf16
{
    const int tid = threadIdx.x;
    const int b0 = blockIdx.x * 4;
    __shared__ __align__(16) float hs[256][4];
    __shared__ __align__(16) float cs[256][4];
    __shared__ __align__(16) float xt[128][4];
    __shared__ __align__(16) float wqp[8][128][4];
    __shared__ __align__(16) float wqs[128][4];
    __shared__ float scp[4][4][128];
    __shared__ float gp[4][4][256];       // gates partials [q][r][u] (u innermost!)
    __shared__ float ves[128];

    if (tid < 128) ves[tid] = ve[tid];
    if (tid < 256) {
        const float4 z = make_float4(0.f, 0.f, 0.f, 0.f);
        *(float4*)hs[tid] = z;
        *(float4*)cs[tid] = z;
    }
    const int u = tid & 255;
    const int ks = tid >> 8;                   // gates k-slice
    const float b_i = bih[u] + bhh[u];
    const float b_f = bih[256 + u] + bhh[256 + u];
    const float b_g = bih[512 + u] + bhh[512 + u];
    const float b_o = bih[768 + u] + bhh[768 + u];
    __syncthreads();

    const int kg = tid >> 6, sb = tid & 63;    // wq: 8 k-groups of 64
    const float* wq_w = WeT + kg * 64 * 128;
    const int n_ = tid & 127, sh = tid >> 7;   // scores: 4 s-slices of 32
    const float* gw = WencT + u * 4;

    for (int t = 0; t < 128; ++t) {
        // ---- wq partials: q=[h,c] (512), k-split 8; thread: s=sb, sb+64 ----
        {
            const float* qb = (kg < 4) ? &hs[kg * 64][0] : &cs[(kg - 4) * 64][0];
            float a0 = 0, a1 = 0, a2 = 0, a3 = 0;
            float c0 = 0, c1 = 0, c2 = 0, c3 = 0;
#pragma unroll 4
            for (int kk = 0; kk < 64; ++kk) {
                const float4 q = *(const float4*)(qb + kk * 4);
                const float w0 = wq_w[kk * 128 + sb];
                const float w1 = wq_w[kk * 128 + sb + 64];
                a0 = fmaf(q.x, w0, a0); a1 = fmaf(q.y, w0, a1);
                a2 = fmaf(q.z, w0, a2); a3 = fmaf(q.w, w0, a3);
                c0 = fmaf(q.x, w1, c0); c1 = fmaf(q.y, w1, c1);
                c2 = fmaf(q.z, w1, c2); c3 = fmaf(q.w, w1, c3);
            }
            *(float4*)wqp[kg][sb] = make_float4(a0, a1, a2, a3);
            *(float4*)wqp[kg][sb + 64] = make_float4(c0, c1, c2, c3);
        }
        __syncthreads();
        if (tid < 128) {
            float4 s = *(const float4*)wqp[0][tid];
#pragma unroll
            for (int g = 1; g < 8; ++g) {
                const float4 p = *(const float4*)wqp[g][tid];
                s.x += p.x; s.y += p.y; s.z += p.z; s.w += p.w;
            }
            *(float4*)wqs[tid] = s;
        }
        __syncthreads();
        // ---- attention scores: thread = (n, s-slice of 32) ----
        {
            const ushort_t* Dp = D + (long)b0 * 16384 + (sh * 32) * 128 + n_;
            float a0 = 0, a1 = 0, a2 = 0, a3 = 0;
#pragma unroll 4
            for (int s = 0; s < 32; ++s) {
                const int ss = sh * 32 + s;
                const float4 wq4 = *(const float4*)wqs[ss];
                const float vv = ves[ss];
                const ushort_t* dp = Dp + s * 128;
                a0 = fmaf(tanh_fast(wq4.x + bf2f(dp[0])),     vv, a0);
                a1 = fmaf(tanh_fast(wq4.y + bf2f(dp[16384])), vv, a1);
                a2 = fmaf(tanh_fast(wq4.z + bf2f(dp[32768])), vv, a2);
                a3 = fmaf(tanh_fast(wq4.w + bf2f(dp[49152])), vv, a3);
            }
            scp[sh][0][n_] = a0; scp[sh][1][n_] = a1;
            scp[sh][2][n_] = a2; scp[sh][3][n_] = a3;
        }
        __syncthreads();
        // ---- softmax + x_tilde: wave w (of first 4) = row w ----
        if (tid < 256) {
            const int w = tid >> 6, lane = tid & 63;
            const float s0 = scp[0][w][lane] + scp[1][w][lane]
                           + scp[2][w][lane] + scp[3][w][lane];
            const float s1 = scp[0][w][lane + 64] + scp[1][w][lane + 64]
                           + scp[2][w][lane + 64] + scp[3][w][lane + 64];
            float mx = fmaxf(s0, s1);
            for (int o = 32; o > 0; o >>= 1) mx = fmaxf(mx, __shfl_xor(mx, o, 64));
            const float e0 = __expf(s0 - mx), e1 = __expf(s1 - mx);
            float sm = e0 + e1;
            for (int o = 32; o > 0; o >>= 1) sm += __shfl_xor(sm, o, 64);
            const float inv = __fdividef(1.0f, sm);
            const float* xp = enc_data + ((long)(b0 + w) * 128 + t) * 128;
            xt[lane][w] = e0 * inv * xp[lane];
            xt[lane + 64][w] = e1 * inv * xp[lane + 64];
        }
        __syncthreads();
        // ---- gates: k-split 2 (192 + 192); thread owns unit u ----
        float acc[4][4];
#pragma unroll
        for (int q = 0; q < 4; ++q)
#pragma unroll
            for (int r = 0; r < 4; ++r) acc[q][r] = 0.0f;
        if (ks == 0) {
#pragma unroll 8
            for (int k = 0; k < 128; ++k) {        // x part
                const float4 wv = *(const float4*)(gw + (long)k * 1024);
                const float4 xv = *(const float4*)xt[k];
                const float wa[4] = {wv.x, wv.y, wv.z, wv.w};
                const float xa[4] = {xv.x, xv.y, xv.z, xv.w};
#pragma unroll
                for (int q = 0; q < 4; ++q)
#pragma unroll
                    for (int r = 0; r < 4; ++r)
                        acc[q][r] = fmaf(wa[q], xa[r], acc[q][r]);
            }
            const float* gw2 = gw + 128 * 1024;    // h part k=0..63
#pragma unroll 8
            for (int k = 0; k < 64; ++k) {
                const float4 wv = *(const float4*)(gw2 + (long)k * 1024);
                const float4 xv = *(const float4*)hs[k];
                const float wa[4] = {wv.x, wv.y, wv.z, wv.w};
                const float xa[4] = {xv.x, xv.y, xv.z, xv.w};
#pragma unroll
                for (int q = 0; q < 4; ++q)
#pragma unroll
                    for (int r = 0; r < 4; ++r)
                        acc[q][r] = fmaf(wa[q], xa[r], acc[q][r]);
            }
        } else {
            const float* gw2 = gw + 192 * 1024;    // h part k=64..255
#pragma unroll 8
            for (int k = 0; k < 192; ++k) {
                const float4 wv = *(const float4*)(gw2 + (long)k * 1024);
                const float4 xv = *(const float4*)hs[64 + k];
                const float wa[4] = {wv.x, wv.y, wv.z, wv.w};
                const float xa[4] = {xv.x, xv.y, xv.z, xv.w};
#pragma unroll
                for (int q = 0; q < 4; ++q)
#pragma unroll
                    for (int r = 0; r < 4; ++r)
                        acc[q][r] = fmaf(wa[q], xa[r], acc[q][r]);
            }
#pragma unroll
            for (int q = 0; q < 4; ++q)
#pragma unroll
                for (int r = 0; r < 4; ++r) gp[q][r][u] = acc[q][r];
        }
        __syncthreads();
        if (ks == 0) {
#pragma unroll
            for (int r = 0; r < 4; ++r) {
                const float iv = sig_fast(acc[0][r] + gp[0][r][u] + b_i);
                const float fv = sig_fast(acc[1][r] + gp[1][r][u] + b_f);
                const float gv = tanh_fast(acc[2][r] + gp[2][r][u] + b_g);
                const float ov = sig_fast(acc[3][r] + gp[3][r][u] + b_o);
                const float cn = fv * cs[u][r] + iv * gv;
                const float hn = ov * tanh_fast(cn);
                cs[u][r] = cn;
                hs[u][r] = hn;
                Hbf[((long)(b0 + r) * 128 + t) * 256 + u] = f2bf(hn);
            }
        }
        __syncthreads();
    }
}

// ---------------------------------------------------------------------------
// Persistent decoder + final MLP: 256 blocks x 512 threads, 4 rows/block.
// ---------------------------------------------------------------------------
__global__ __launch_bounds__(512) void dec_persist(
    const float* __restrict__ dec_data,   // [1024][128]
    const ushort_t* __restrict__ UH2,     // [1024][256][128] bf16
    const ushort_t* __restrict__ Hb,      // [1024][128][256] bf16
    const float* __restrict__ WdT,        // [512][256]
    const float* __restrict__ vd,         // [256]
    const float* __restrict__ WdecT,      // [257][1024]
    const float* __restrict__ bih, const float* __restrict__ bhh,
    const float* __restrict__ wt_w, const float* __restrict__ wt_b,
    const float* __restrict__ l1T,        // [512][256]
    const float* __restrict__ l1_b,
    const float* __restrict__ l2_w, const float* __restrict__ l2_b,
    float* __restrict__ out)
{
    const int tid = threadIdx.x;
    const int b0 = blockIdx.x * 4;
    __shared__ __align__(16) float ds4[256][4];
    __shared__ __align__(16) float ss4[256][4];
    __shared__ __align__(16) float wqp[4][256][4];
    __shared__ __align__(16) float wqs[256][4];
    __shared__ float scp[4][4][128];
    __shared__ __align__(16) float beta[128][4];
    __shared__ __align__(16) float ctxp[256][4];
    __shared__ __align__(16) float ctx4[256][4];
    __shared__ float gp[4][4][256];
    __shared__ __align__(16) float o14[256][4];
    __shared__ float vds[256];
    __shared__ float wt1s[256];
    __shared__ float l2s[256];
    __shared__ __align__(16) float yts[4];

    const int u = tid & 255;
    const int ks = tid >> 8;
    if (tid < 256) {
        vds[tid] = vd[tid];
        wt1s[tid] = wt_w[1 + tid];
        l2s[tid] = l2_w[tid];
        const float4 z = make_float4(0.f, 0.f, 0.f, 0.f);
        *(float4*)ds4[tid] = z;
        *(float4*)ss4[tid] = z;
    }
    const float b_i = bih[u] + bhh[u];
    const float b_f = bih[256 + u] + bhh[256 + u];
    const float b_g = bih[512 + u] + bhh[512 + u];
    const float b_o = bih[768 + u] + bhh[768 + u];
    __syncthreads();

    const int kg = tid >> 7, mb = tid & 127;  // wq: 4 k-groups of 128; m=mb,mb+128
    const float* wq_w = WdT + kg * 128 * 256;
    const int tp = tid & 127, uh = tid >> 7;  // scores: 4 u-slices of 64
    const float* gw = WdecT + u * 4;

    for (int td = 0; td < 128; ++td) {
        // ---- wq partials ----
        {
            const float* qb = (kg < 2) ? &ds4[kg * 128][0] : &ss4[(kg - 2) * 128][0];
            float a0 = 0, a1 = 0, a2 = 0, a3 = 0;
            float c0 = 0, c1 = 0, c2 = 0, c3 = 0;
#pragma unroll 4
            for (int kk = 0; kk < 128; ++kk) {
                const float4 q = *(const float4*)(qb + kk * 4);
                const float w0 = wq_w[kk * 256 + mb];
                const float w1 = wq_w[kk * 256 + mb + 128];
                a0 = fmaf(q.x, w0, a0); a1 = fmaf(q.y, w0, a1);
                a2 = fmaf(q.z, w0, a2); a3 = fmaf(q.w, w0, a3);
                c0 = fmaf(q.x, w1, c0); c1 = fmaf(q.y, w1, c1);
                c2 = fmaf(q.z, w1, c2); c3 = fmaf(q.w, w1, c3);
            }
            *(float4*)wqp[kg][mb] = make_float4(a0, a1, a2, a3);
            *(float4*)wqp[kg][mb + 128] = make_float4(c0, c1, c2, c3);
        }
        __syncthreads();
        if (tid < 256) {
            const float4 p0 = *(const float4*)wqp[0][tid];
            const float4 p1 = *(const float4*)wqp[1][tid];
            const float4 p2 = *(const float4*)wqp[2][tid];
            const float4 p3 = *(const float4*)wqp[3][tid];
            *(float4*)wqs[tid] = make_float4(p0.x + p1.x + p2.x + p3.x,
                                             p0.y + p1.y + p2.y + p3.y,
                                             p0.z + p1.z + p2.z + p3.z,
                                             p0.w + p1.w + p2.w + p3.w);
        }
        __syncthreads();
        // ---- temporal scores: thread = (t', u-slice of 64) ----
        {
            const ushort_t* up = UH2 + (long)b0 * 32768 + (uh * 64) * 128 + tp;
            float a0 = 0, a1 = 0, a2 = 0, a3 = 0;
#pragma unroll 4
            for (int uu = 0; uu < 64; ++uu) {
                const int ui = uh * 64 + uu;
                const float4 wq4 = *(const float4*)wqs[ui];
                const float vv = vds[ui];
                const ushort_t* p = up + uu * 128;
                a0 = fmaf(tanh_fast(wq4.x + bf2f(p[0])),     vv, a0);
                a1 = fmaf(tanh_fast(wq4.y + bf2f(p[32768])), vv, a1);
                a2 = fmaf(tanh_fast(wq4.z + bf2f(p[65536])), vv, a2);
                a3 = fmaf(tanh_fast(wq4.w + bf2f(p[98304])), vv, a3);
            }
            scp[uh][0][tp] = a0; scp[uh][1][tp] = a1;
            scp[uh][2][tp] = a2; scp[uh][3][tp] = a3;
        }
        __syncthreads();
        // ---- softmax -> beta ----
        if (tid < 256) {
            const int w = tid >> 6, lane = tid & 63;
            const float s0 = scp[0][w][lane] + scp[1][w][lane]
                           + scp[2][w][lane] + scp[3][w][lane];
            const float s1 = scp[0][w][lane + 64] + scp[1][w][lane + 64]
                           + scp[2][w][lane + 64] + scp[3][w][lane + 64];
            float mx = fmaxf(s0, s1);
            for (int o = 32; o > 0; o >>= 1) mx = fmaxf(mx, __shfl_xor(mx, o, 64));
            const float e0 = __expf(s0 - mx), e1 = __expf(s1 - mx);
            float sm = e0 + e1;
            for (int o = 32; o > 0; o >>= 1) sm += __shfl_xor(sm, o, 64);
            const float inv = __fdividef(1.0f, sm);
            beta[lane][w] = e0 * inv;
            beta[lane + 64][w] = e1 * inv;
        }
        __syncthreads();
        // ---- ctx: m = u, s-split 2 ----
        {
            const ushort_t* hp = Hb + (long)b0 * 32768 + (ks * 64) * 256 + u;
            float c0 = 0, c1 = 0, c2 = 0, c3 = 0;
#pragma unroll 4
            for (int s = 0; s < 64; ++s) {
                const float4 bt = *(const float4*)beta[ks * 64 + s];
                const ushort_t* p = hp + s * 256;
                c0 = fmaf(bt.x, bf2f(p[0]),     c0);
                c1 = fmaf(bt.y, bf2f(p[32768]), c1);
                c2 = fmaf(bt.z, bf2f(p[65536]), c2);
                c3 = fmaf(bt.w, bf2f(p[98304]), c3);
            }
            if (ks == 1) {
                *(float4*)ctxp[u] = make_float4(c0, c1, c2, c3);
            } else {
                *(float4*)ctx4[u] = make_float4(c0, c1, c2, c3);
            }
        }
        __syncthreads();
        if (tid < 256) {
            const float4 a = *(const float4*)ctx4[tid];
            const float4 b = *(const float4*)ctxp[tid];
            *(float4*)ctx4[tid] = make_float4(a.x + b.x, a.y + b.y,
                                              a.z + b.z, a.w + b.w);
        }
        __syncthreads();
        if (td == 127) break;
        // ---- y_tilde ----
        if (tid < 256) {
            const int w = tid >> 6, lane = tid & 63;
            float s = ctx4[lane][w] * wt1s[lane]
                    + ctx4[lane + 64][w] * wt1s[lane + 64]
                    + ctx4[lane + 128][w] * wt1s[lane + 128]
                    + ctx4[lane + 192][w] * wt1s[lane + 192];
            for (int o = 32; o > 0; o >>= 1) s += __shfl_xor(s, o, 64);
            if (lane == 0)
                yts[w] = s + wt_b[0] + wt_w[0] * dec_data[(long)(b0 + w) * 128 + td];
        }
        __syncthreads();
        // ---- gates: k-split 2 (y+128 / 128) ----
        float acc[4][4];
        if (ks == 0) {
            const float4 wv0 = *(const float4*)gw;
            const float4 y4 = *(const float4*)yts;
            const float wa0[4] = {wv0.x, wv0.y, wv0.z, wv0.w};
            const float ya[4] = {y4.x, y4.y, y4.z, y4.w};
#pragma unroll
            for (int q = 0; q < 4; ++q)
#pragma unroll
                for (int r = 0; r < 4; ++r) acc[q][r] = wa0[q] * ya[r];
            const float* gw2 = gw + 1024;
#pragma unroll 8
            for (int k = 0; k < 128; ++k) {
                const float4 wv = *(const float4*)(gw2 + (long)k * 1024);
                const float4 xv = *(const float4*)ds4[k];
                const float wa[4] = {wv.x, wv.y, wv.z, wv.w};
                const float xa[4] = {xv.x, xv.y, xv.z, xv.w};
#pragma unroll
                for (int q = 0; q < 4; ++q)
#pragma unroll
                    for (int r = 0; r < 4; ++r)
                        acc[q][r] = fmaf(wa[q], xa[r], acc[q][r]);
            }
        } else {
#pragma unroll
            for (int q = 0; q < 4; ++q)
#pragma unroll
                for (int r = 0; r < 4; ++r) acc[q][r] = 0.0f;
            const float* gw2 = gw + 1024 + 128 * 1024;
#pragma unroll 8
            for (int k = 0; k < 128; ++k) {
                const float4 wv = *(const float4*)(gw2 + (long)k * 1024);
                const float4 xv = *(const float4*)ds4[128 + k];
                const float wa[4] = {wv.x, wv.y, wv.z, wv.w};
                const float xa[4] = {xv.x, xv.y, xv.z, xv.w};
#pragma unroll
                for (int q = 0; q < 4; ++q)
#pragma unroll
                    for (int r = 0; r < 4; ++r)
                        acc[q][r] = fmaf(wa[q], xa[r], acc[q][r]);
            }
#pragma unroll
            for (int q = 0; q < 4; ++q)
#pragma unroll
                for (int r = 0; r < 4; ++r) gp[q][r][u] = acc[q][r];
        }
        __syncthreads();
        if (ks == 0) {
#pragma unroll
            for (int r = 0; r < 4; ++r) {
                const float iv = sig_fast(acc[0][r] + gp[0][r][u] + b_i);
                const float fv = sig_fast(acc[1][r] + gp[1][r][u] + b_f);
                const float gv = tanh_fast(acc[2][r] + gp[2][r][u] + b_g);
                const float ov = sig_fast(acc[3][r] + gp[3][r][u] + b_o);
                const float sn = fv * ss4[u][r] + iv * gv;
                const float dn = ov * tanh_fast(sn);
                ss4[u][r] = sn;
                ds4[u][r] = dn;
            }
        }
        __syncthreads();
    }
    // ---- final MLP: l1 k-split 2 (ds / ctx), then l2 wave-reduce ----
    {
        const float* src = l1T + ks * 256 * 256;
        float a0 = 0, a1 = 0, a2 = 0, a3 = 0;
#pragma unroll 4
        for (int k = 0; k < 256; ++k) {
            const float w = src[k * 256 + u];
            const float4 q = (ks == 0) ? *(const float4*)ds4[k]
                                       : *(const float4*)ctx4[k];
            a0 = fmaf(q.x, w, a0); a1 = fmaf(q.y, w, a1);
            a2 = fmaf(q.z, w, a2); a3 = fmaf(q.w, w, a3);
        }
        if (ks == 1) {
            gp[0][0][u] = a0; gp[0][1][u] = a1; gp[0][2][u] = a2; gp[0][3][u] = a3;
        } else {
            gp[1][0][u] = a0; gp[1][1][u] = a1; gp[1][2][u] = a2; gp[1][3][u] = a3;
        }
    }
    __syncthreads();
    if (tid < 256) {
        const float bb = l1_b[tid];
        *(float4*)o14[tid] = make_float4(
            fmaxf(gp[0][0][tid] + gp[1][0][tid] + bb, 0.f),
            fmaxf(gp[0][1][tid] + gp[1][1][tid] + bb, 0.f),
            fmaxf(gp[0][2][tid] + gp[1][2][tid] + bb, 0.f),
            fmaxf(gp[0][3][tid] + gp[1][3][tid] + bb, 0.f));
    }
    __syncthreads();
    if (tid < 256) {
        const int w = tid >> 6, lane = tid & 63;
        float s = o14[lane][w] * l2s[lane]
                + o14[lane + 64][w] * l2s[lane + 64]
                + o14[lane + 128][w] * l2s[lane + 128]
                + o14[lane + 192][w] * l2s[lane + 192];
        for (int o = 32; o > 0; o >>= 1) s += __shfl_xor(s, o, 64);
        if (lane == 0) out[b0 + w] = s + l2_b[0];
    }
}

extern "C" void kernel_launch(void* const* d_in, const int* in_sizes, int n_in,
                              void* d_out, int out_size, void* d_ws, size_t ws_size,
                              hipStream_t stream)
{
    const float* enc_data = (const float*)d_in[0];
    const float* dec_data = (const float*)d_in[1];
    const float* enc_Wih  = (const float*)d_in[2];
    const float* enc_Whh  = (const float*)d_in[3];
    const float* enc_bih  = (const float*)d_in[4];
    const float* enc_bhh  = (const float*)d_in[5];
    const float* We   = (const float*)d_in[6];
    const float* Ue   = (const float*)d_in[7];
    const float* ve   = (const float*)d_in[8];
    const float* Wd   = (const float*)d_in[9];
    const float* Ud   = (const float*)d_in[10];
    const float* vd   = (const float*)d_in[11];
    const float* wt_w = (const float*)d_in[12];
    const float* wt_b = (const float*)d_in[13];
    const float* dec_Wih = (const float*)d_in[14];
    const float* dec_Whh = (const float*)d_in[15];
    const float* dec_bih = (const float*)d_in[16];
    const float* dec_bhh = (const float*)d_in[17];
    const float* l1_w = (const float*)d_in[18];
    const float* l1_b = (const float*)d_in[19];
    const float* l2_w = (const float*)d_in[20];
    const float* l2_b = (const float*)d_in[21];

    // ---- workspace layout (~171 MB) ----
    ushort_t* Dbf  = (ushort_t*)d_ws;                         // 32 MB
    ushort_t* Hbf  = Dbf + (long)BATCH * TT * NN;             // 64 MB
    ushort_t* UHbf = Hbf + (long)BATCH * TT * MM;             // 64 MB
    float* WencT = (float*)(UHbf + (long)BATCH * MM * TT);
    float* WdecT = WencT + 384 * 1024;
    float* WeT   = WdecT + 257 * 1024;
    float* WdT   = WeT + 512 * 128;
    float* l1T   = WdT + 512 * 256;

    prep_encw_k<<<1536, 256, 0, stream>>>(enc_Wih, enc_Whh, WencT);
    prep_decw_k<<<1028, 256, 0, stream>>>(dec_Wih, dec_Whh, WdecT);
    transpose_k<<<(128 * 512 + 255) / 256, 256, 0, stream>>>(We, WeT, 128, 512);
    transpose_k<<<(256 * 512 + 255) / 256, 256, 0, stream>>>(Wd, WdT, 256, 512);
    transpose_k<<<(256 * 512 + 255) / 256, 256, 0, stream>>>(l1_w, l1T, 256, 512);

    // D[b][s][n] = sum_t Ue[s][t] * enc_data[b][t][n]
    gemm_k<false, true, true, false><<<dim3(NN / 64, TT / 64, BATCH), 256, 0, stream>>>(
        Ue, TT, 0, TT,
        nullptr, 0, 0,
        enc_data, NN, (long)TT * NN,
        nullptr, 0,
        nullptr,
        Dbf, NN, (long)TT * NN);

    enc_persist<<<256, 512, 0, stream>>>(enc_data, Dbf, WeT, ve, WencT,
                                         enc_bih, enc_bhh, Hbf);

    // UH2[b][u][t'] = sum_m Ud[u][m] * H[b][t'][m]
    gemm_k<true, false, true, false><<<dim3(TT / 64, MM / 64, BATCH), 256, 0, stream>>>(
        Ud, MM, 0, MM,
        nullptr, 0, 0,
        Hbf, MM, (long)TT * MM,
        nullptr, 0,
        nullptr,
        UHbf, TT, (long)MM * TT);

    dec_persist<<<256, 512, 0, stream>>>(dec_data, UHbf, Hbf, WdT, vd, WdecT,
                                         dec_bih, dec_bhh, wt_w, wt_b,
                                         l1T, l1_b, l2_w, l2_b, (float*)d_out);
}

// Round 4
// 10486.653 us; speedup vs baseline: 1.8126x; 1.8126x over previous
//
#include <hip/hip_runtime.h>

typedef unsigned short ushort_t;

static constexpr int BATCH = 1024;
static constexpr int TT = 128;   // T
static constexpr int NN = 128;   // N
static constexpr int MM = 256;   // M == P

__device__ __forceinline__ float bf2f(ushort_t u) {
    union { unsigned int i; float f; } v;
    v.i = ((unsigned int)u) << 16;
    return v.f;
}
__device__ __forceinline__ ushort_t f2bf(float f) {
    union { unsigned int i; float f; } v;
    v.f = f;
    unsigned int i = v.i;
    return (ushort_t)((i + 0x7FFFu + ((i >> 16) & 1u)) >> 16);
}
// unpack 8 bf16 (16B) -> 8 fp32
__device__ __forceinline__ void unp8(const int4 w, float* o) {
    union { unsigned int i; float f; } v;
    v.i = ((unsigned int)w.x) << 16;        o[0] = v.f;
    v.i = ((unsigned int)w.x) & 0xffff0000u; o[1] = v.f;
    v.i = ((unsigned int)w.y) << 16;        o[2] = v.f;
    v.i = ((unsigned int)w.y) & 0xffff0000u; o[3] = v.f;
    v.i = ((unsigned int)w.z) << 16;        o[4] = v.f;
    v.i = ((unsigned int)w.z) & 0xffff0000u; o[5] = v.f;
    v.i = ((unsigned int)w.w) << 16;        o[6] = v.f;
    v.i = ((unsigned int)w.w) & 0xffff0000u; o[7] = v.f;
}
__device__ __forceinline__ float tanh_fast(float x) {
    x = fminf(9.0f, fmaxf(-9.0f, x));
    float e = __expf(2.0f * x);
    return 1.0f - __fdividef(2.0f, e + 1.0f);
}
__device__ __forceinline__ float sig_fast(float x) {
    x = fminf(30.0f, fmaxf(-30.0f, x));
    return __fdividef(1.0f, 1.0f + __expf(-x));
}

// ---------------------------------------------------------------------------
// Generic tiled GEMM (verified R1) — only for the two one-time precomputes.
// ---------------------------------------------------------------------------
template<bool WBF16, bool TRANSW, bool CBF16, bool RELU>
__global__ __launch_bounds__(256) void gemm_k(
    const float* __restrict__ A1, int lda1, long sA1z, int K1,
    const float* __restrict__ A2, int lda2, int K2,
    const void* __restrict__ W1v, int ldw1, long sW1z,
    const void* __restrict__ W2v, int ldw2,
    const float* __restrict__ bias1,
    void* __restrict__ Cv, int ldc, long sCz)
{
    __shared__ float As[32][68];
    __shared__ float Ws[32][68];
    const int tid = threadIdx.x;
    const int z = blockIdx.z;
    const int m0 = blockIdx.y * 64;
    const int g0 = blockIdx.x * 64;
    const int tm = tid & 15, tn = tid >> 4;
    float acc[4][4];
#pragma unroll
    for (int i = 0; i < 4; ++i)
#pragma unroll
        for (int j = 0; j < 4; ++j) acc[i][j] = 0.0f;

    for (int phase = 0; phase < 2; ++phase) {
        const float* A = (phase == 0) ? (A1 + (long)z * sA1z) : A2;
        const int lda = (phase == 0) ? lda1 : lda2;
        const int K = (phase == 0) ? K1 : K2;
        const int ldw = (phase == 0) ? ldw1 : ldw2;
        const void* Wv = (phase == 0) ? W1v : W2v;
        const long woff = (phase == 0) ? (long)z * sW1z : 0;
        if (A == nullptr || Wv == nullptr || K <= 0) continue;

        for (int k0 = 0; k0 < K; k0 += 32) {
            const int rem = K - k0;
            {
                const int tr0 = tid >> 3;
                const int tk = (tid & 7) * 4;
#pragma unroll
                for (int pass = 0; pass < 2; ++pass) {
                    const int m = tr0 + pass * 32;
                    const float* p = A + (long)(m0 + m) * lda + k0 + tk;
#pragma unroll
                    for (int j = 0; j < 4; ++j) {
                        float v = 0.0f;
                        if (tk + j < rem) v = p[j];
                        As[tk + j][m] = v;
                    }
                }
            }
            if constexpr (TRANSW) {
                const float* W = (const float*)Wv + woff;
                const int gq = (tid & 15) * 4;
                const int kr = tid >> 4;
#pragma unroll
                for (int pass = 0; pass < 2; ++pass) {
                    const int k = kr + pass * 16;
                    const float* p = W + (long)(k0 + k) * ldw + g0 + gq;
                    const bool ok = (k < rem);
#pragma unroll
                    for (int j = 0; j < 4; ++j) {
                        float v = 0.0f;
                        if (ok) v = p[j];
                        Ws[k][gq + j] = v;
                    }
                }
            } else if constexpr (WBF16) {
                const ushort_t* W = (const ushort_t*)Wv + woff;
                const int g = tid >> 2;
                const int tk = (tid & 3) * 8;
                const ushort_t* p = W + (long)(g0 + g) * ldw + k0 + tk;
#pragma unroll
                for (int j = 0; j < 8; ++j) {
                    float v = 0.0f;
                    if (tk + j < rem) v = bf2f(p[j]);
                    Ws[tk + j][g] = v;
                }
            } else {
                const float* W = (const float*)Wv + woff;
                const int tr0 = tid >> 3;
                const int tk = (tid & 7) * 4;
#pragma unroll
                for (int pass = 0; pass < 2; ++pass) {
                    const int g = tr0 + pass * 32;
                    const float* p = W + (long)(g0 + g) * ldw + k0 + tk;
#pragma unroll
                    for (int j = 0; j < 4; ++j) {
                        float v = 0.0f;
                        if (tk + j < rem) v = p[j];
                        Ws[tk + j][g] = v;
                    }
                }
            }
            __syncthreads();
#pragma unroll
            for (int kk = 0; kk < 32; ++kk) {
                const float4 av = *(const float4*)&As[kk][tm * 4];
                const float4 bv = *(const float4*)&Ws[kk][tn * 4];
                const float a[4] = {av.x, av.y, av.z, av.w};
                const float b[4] = {bv.x, bv.y, bv.z, bv.w};
#pragma unroll
                for (int i = 0; i < 4; ++i)
#pragma unroll
                    for (int j = 0; j < 4; ++j)
                        acc[i][j] = fmaf(a[i], b[j], acc[i][j]);
            }
            __syncthreads();
        }
    }
#pragma unroll
    for (int i = 0; i < 4; ++i) {
        const long m = m0 + tm * 4 + i;
#pragma unroll
        for (int j = 0; j < 4; ++j) {
            const int g = g0 + tn * 4 + j;
            float v = acc[i][j];
            if (bias1) v += bias1[g];
            if (RELU) v = fmaxf(v, 0.0f);
            if constexpr (CBF16)
                ((ushort_t*)Cv)[(long)z * sCz + m * ldc + g] = f2bf(v);
            else
                ((float*)Cv)[(long)z * sCz + m * ldc + g] = v;
        }
    }
}

// ---------------------------------------------------------------------------
// Weight prep
// ---------------------------------------------------------------------------
__global__ void prep_encw_k(const float* __restrict__ Wih, const float* __restrict__ Whh,
                            float* __restrict__ dst) {
    int i = blockIdx.x * 256 + threadIdx.x;
    if (i >= 384 * 1024) return;
    int k = i >> 10, col = i & 1023, u = col >> 2, q = col & 3, g = q * 256 + u;
    dst[i] = (k < 128) ? Wih[g * 128 + k] : Whh[g * 256 + (k - 128)];
}

__global__ void prep_decw_k(const float* __restrict__ Wih, const float* __restrict__ Whh,
                            float* __restrict__ dst) {
    int i = blockIdx.x * 256 + threadIdx.x;
    if (i >= 257 * 1024) return;
    int k = i >> 10, col = i & 1023, u = col >> 2, q = col & 3, g = q * 256 + u;
    dst[i] = (k == 0) ? Wih[g] : Whh[g * 256 + (k - 1)];
}

__global__ void transpose_k(const float* __restrict__ src, float* __restrict__ dst,
                            int R, int C) {
    int i = blockIdx.x * 256 + threadIdx.x;
    if (i < R * C) { int r = i / C, c = i - r * C; dst[c * R + r] = src[i]; }
}

// ---------------------------------------------------------------------------
// Persistent encoder: 256 blocks x 512 threads, 4 rows/block. All bf16
// streams read as int4 (8 bf16, 16B/lane).
// ---------------------------------------------------------------------------
__global__ __launch_bounds__(512) void enc_persist(
    const float* __restrict__ enc_data,   // [1024][128][128]
    const ushort_t* __restrict__ D,       // [1024][128][128] bf16
    const float* __restrict__ WeT,        // [512][128]
    const float* __restrict__ ve,         // [128]
    const float* __restrict__ WencT,      // [384][1024]
    const float* __restrict__ bih, const float* __restrict__ bhh,
    ushort_t* __restrict__ Hbf)           // [1024][128][256] bf16
{
    const int tid = threadIdx.x;
    const int b0 = blockIdx.x * 4;
    __shared__ __align__(16) float hs[256][4];
    __shared__ __align__(16) float cs[256][4];
    __shared__ __align__(16) float xt[128][4];
    __shared__ __align__(16) float wqp[16][128][4];   // wq partials [kg][s][r]
    __shared__ __align__(16) float wqs[128][4];       // [s][r]
    __shared__ __align__(16) float scp[8][4][128];    // score partials [sslice][r][n]
    __shared__ float gp[4][4][256];                   // gates partials [q][r][u]
    __shared__ float ves[128];

    if (tid < 128) ves[tid] = ve[tid];
    if (tid < 256) {
        const float4 z = make_float4(0.f, 0.f, 0.f, 0.f);
        *(float4*)hs[tid] = z;
        *(float4*)cs[tid] = z;
    }
    const int u = tid & 255;
    const int ks = tid >> 8;
    const float b_i = bih[u] + bhh[u];
    const float b_f = bih[256 + u] + bhh[256 + u];
    const float b_g = bih[512 + u] + bhh[512 + u];
    const float b_o = bih[768 + u] + bhh[768 + u];
    __syncthreads();

    // wq mapping: 16 k-groups of 32 (over [h;c]), 32 s-vecs of 4
    const int kgq = tid >> 5, sv = tid & 31;
    const float* wq_w = WeT + kgq * 32 * 128;
    const float* qbase = (kgq < 8) ? &hs[kgq * 32][0] : &cs[(kgq - 8) * 32][0];
    // scores mapping: 16 n-vecs of 8, 4 rows, 8 s-slices of 16
    const int nv = tid & 15, srow = (tid >> 4) & 3, ssl = tid >> 6;
    const ushort_t* Dp0 = D + (long)(b0 + srow) * 16384 + (ssl * 16) * 128 + nv * 8;
    const float* gw = WencT + u * 4;

    for (int t = 0; t < 128; ++t) {
        // ---- wq partials: a[m][r], float4 weight loads ----
        {
            float a[4][4];
#pragma unroll
            for (int m = 0; m < 4; ++m)
#pragma unroll
                for (int r = 0; r < 4; ++r) a[m][r] = 0.0f;
#pragma unroll 4
            for (int kk = 0; kk < 32; ++kk) {
                const float4 w4 = *(const float4*)(wq_w + kk * 128 + sv * 4);
                const float4 q4 = *(const float4*)(qbase + kk * 4);
                const float wa[4] = {w4.x, w4.y, w4.z, w4.w};
                const float qa[4] = {q4.x, q4.y, q4.z, q4.w};
#pragma unroll
                for (int m = 0; m < 4; ++m)
#pragma unroll
                    for (int r = 0; r < 4; ++r)
                        a[m][r] = fmaf(wa[m], qa[r], a[m][r]);
            }
#pragma unroll
            for (int m = 0; m < 4; ++m)
                *(float4*)wqp[kgq][sv * 4 + m] = make_float4(a[m][0], a[m][1], a[m][2], a[m][3]);
        }
        __syncthreads();
        if (tid < 128) {
            float4 s = *(const float4*)wqp[0][tid];
#pragma unroll
            for (int g = 1; g < 16; ++g) {
                const float4 p = *(const float4*)wqp[g][tid];
                s.x += p.x; s.y += p.y; s.z += p.z; s.w += p.w;
            }
            *(float4*)wqs[tid] = s;
        }
        __syncthreads();
        // ---- attention scores: vectorized D reads (8 bf16 per load) ----
        {
            float a[8];
#pragma unroll
            for (int j = 0; j < 8; ++j) a[j] = 0.0f;
#pragma unroll 4
            for (int s = 0; s < 16; ++s) {
                const int sg = ssl * 16 + s;
                const float wq = wqs[sg][srow];
                const float vv = ves[sg];
                const int4 wv = *(const int4*)(Dp0 + s * 128);
                float d[8];
                unp8(wv, d);
#pragma unroll
                for (int j = 0; j < 8; ++j)
                    a[j] = fmaf(tanh_fast(wq + d[j]), vv, a[j]);
            }
            *(float4*)&scp[ssl][srow][nv * 8]     = make_float4(a[0], a[1], a[2], a[3]);
            *(float4*)&scp[ssl][srow][nv * 8 + 4] = make_float4(a[4], a[5], a[6], a[7]);
        }
        __syncthreads();
        // ---- softmax + x_tilde: wave w = row w (tid<256) ----
        if (tid < 256) {
            const int w = tid >> 6, lane = tid & 63;
            float s0 = 0.0f, s1 = 0.0f;
#pragma unroll
            for (int g = 0; g < 8; ++g) {
                s0 += scp[g][w][lane];
                s1 += scp[g][w][lane + 64];
            }
            float mx = fmaxf(s0, s1);
            for (int o = 32; o > 0; o >>= 1) mx = fmaxf(mx, __shfl_xor(mx, o, 64));
            const float e0 = __expf(s0 - mx), e1 = __expf(s1 - mx);
            float sm = e0 + e1;
            for (int o = 32; o > 0; o >>= 1) sm += __shfl_xor(sm, o, 64);
            const float inv = __fdividef(1.0f, sm);
            const float* xp = enc_data + ((long)(b0 + w) * 128 + t) * 128;
            xt[lane][w] = e0 * inv * xp[lane];
            xt[lane + 64][w] = e1 * inv * xp[lane + 64];
        }
        __syncthreads();
        // ---- gates: k-split 2 (192 + 192) ----
        float acc[4][4];
#pragma unroll
        for (int q = 0; q < 4; ++q)
#pragma unroll
            for (int r = 0; r < 4; ++r) acc[q][r] = 0.0f;
        if (ks == 0) {
#pragma unroll 8
            for (int k = 0; k < 128; ++k) {
                const float4 wv = *(const float4*)(gw + (long)k * 1024);
                const float4 xv = *(const float4*)xt[k];
                const float wa[4] = {wv.x, wv.y, wv.z, wv.w};
                const float xa[4] = {xv.x, xv.y, xv.z, xv.w};
#pragma unroll
                for (int q = 0; q < 4; ++q)
#pragma unroll
                    for (int r = 0; r < 4; ++r)
                        acc[q][r] = fmaf(wa[q], xa[r], acc[q][r]);
            }
            const float* gw2 = gw + 128 * 1024;
#pragma unroll 8
            for (int k = 0; k < 64; ++k) {
                const float4 wv = *(const float4*)(gw2 + (long)k * 1024);
                const float4 xv = *(const float4*)hs[k];
                const float wa[4] = {wv.x, wv.y, wv.z, wv.w};
                const float xa[4] = {xv.x, xv.y, xv.z, xv.w};
#pragma unroll
                for (int q = 0; q < 4; ++q)
#pragma unroll
                    for (int r = 0; r < 4; ++r)
                        acc[q][r] = fmaf(wa[q], xa[r], acc[q][r]);
            }
        } else {
            const float* gw2 = gw + 192 * 1024;
#pragma unroll 8
            for (int k = 0; k < 192; ++k) {
                const float4 wv = *(const float4*)(gw2 + (long)k * 1024);
                const float4 xv = *(const float4*)hs[64 + k];
                const float wa[4] = {wv.x, wv.y, wv.z, wv.w};
                const float xa[4] = {xv.x, xv.y, xv.z, xv.w};
#pragma unroll
                for (int q = 0; q < 4; ++q)
#pragma unroll
                    for (int r = 0; r < 4; ++r)
                        acc[q][r] = fmaf(wa[q], xa[r], acc[q][r]);
            }
#pragma unroll
            for (int q = 0; q < 4; ++q)
#pragma unroll
                for (int r = 0; r < 4; ++r) gp[q][r][u] = acc[q][r];
        }
        __syncthreads();
        if (ks == 0) {
#pragma unroll
            for (int r = 0; r < 4; ++r) {
                const float iv = sig_fast(acc[0][r] + gp[0][r][u] + b_i);
                const float fv = sig_fast(acc[1][r] + gp[1][r][u] + b_f);
                const float gv = tanh_fast(acc[2][r] + gp[2][r][u] + b_g);
                const float ov = sig_fast(acc[3][r] + gp[3][r][u] + b_o);
                const float cn = fv * cs[u][r] + iv * gv;
                const float hn = ov * tanh_fast(cn);
                cs[u][r] = cn;
                hs[u][r] = hn;
                Hbf[((long)(b0 + r) * 128 + t) * 256 + u] = f2bf(hn);
            }
        }
        __syncthreads();
    }
}

// ---------------------------------------------------------------------------
// Persistent decoder + final MLP: 256 blocks x 512 threads, 4 rows/block.
// UH2 and H streams read as int4 (8 bf16 per load).
// ---------------------------------------------------------------------------
__global__ __launch_bounds__(512) void dec_persist(
    const float* __restrict__ dec_data,   // [1024][128]
    const ushort_t* __restrict__ UH2,     // [1024][256][128] bf16
    const ushort_t* __restrict__ Hb,      // [1024][128][256] bf16
    const float* __restrict__ WdT,        // [512][256]
    const float* __restrict__ vd,         // [256]
    const float* __restrict__ WdecT,      // [257][1024]
    const float* __restrict__ bih, const float* __restrict__ bhh,
    const float* __restrict__ wt_w, const float* __restrict__ wt_b,
    const float* __restrict__ l1T,        // [512][256]
    const float* __restrict__ l1_b,
    const float* __restrict__ l2_w, const float* __restrict__ l2_b,
    float* __restrict__ out)
{
    const int tid = threadIdx.x;
    const int b0 = blockIdx.x * 4;
    __shared__ __align__(16) float ds4[256][4];
    __shared__ __align__(16) float ss4[256][4];
    __shared__ __align__(16) float wqp[8][256][4];    // [kg][m][r]
    __shared__ __align__(16) float wqs[256][4];       // [m][r]
    __shared__ __align__(16) float scp[8][4][128];    // [uslice][r][t']
    __shared__ __align__(16) float beta[128][4];
    __shared__ __align__(16) float ctxp[4][4][256];   // [sslice][r][m]
    __shared__ __align__(16) float ctx4[256][4];
    __shared__ float gp[4][4][256];
    __shared__ __align__(16) float o14[256][4];
    __shared__ float vds[256];
    __shared__ float wt1s[256];
    __shared__ float l2s[256];
    __shared__ __align__(16) float yts[4];

    const int u = tid & 255;
    const int ks = tid >> 8;
    if (tid < 256) {
        vds[tid] = vd[tid];
        wt1s[tid] = wt_w[1 + tid];
        l2s[tid] = l2_w[tid];
        const float4 z = make_float4(0.f, 0.f, 0.f, 0.f);
        *(float4*)ds4[tid] = z;
        *(float4*)ss4[tid] = z;
    }
    const float b_i = bih[u] + bhh[u];
    const float b_f = bih[256 + u] + bhh[256 + u];
    const float b_g = bih[512 + u] + bhh[512 + u];
    const float b_o = bih[768 + u] + bhh[768 + u];
    __syncthreads();

    // wq mapping: 8 k-groups of 64 (over [d;s]), 64 m-vecs of 4
    const int kgq = tid >> 6, mv = tid & 63;
    const float* wq_w = WdT + kgq * 64 * 256;
    const float* qbase = (kgq < 4) ? &ds4[kgq * 64][0] : &ss4[(kgq - 4) * 64][0];
    // scores mapping: 16 t'-vecs of 8, 4 rows, 8 u-slices of 32
    const int tv = tid & 15, srow = (tid >> 4) & 3, usl = tid >> 6;
    const ushort_t* up0 = UH2 + ((long)(b0 + srow) * 256 + usl * 32) * 128 + tv * 8;
    // ctx mapping: 32 m-vecs of 8, 4 rows, 4 s-slices of 32
    const int mv8 = tid & 31, crow = (tid >> 5) & 3, ssl2 = tid >> 7;
    const ushort_t* hp0 = Hb + ((long)(b0 + crow) * 128 + ssl2 * 32) * 256 + mv8 * 8;
    const float* gw = WdecT + u * 4;

    for (int td = 0; td < 128; ++td) {
        // ---- wq partials: a[m][r], float4 weight loads ----
        {
            float a[4][4];
#pragma unroll
            for (int m = 0; m < 4; ++m)
#pragma unroll
                for (int r = 0; r < 4; ++r) a[m][r] = 0.0f;
#pragma unroll 4
            for (int kk = 0; kk < 64; ++kk) {
                const float4 w4 = *(const float4*)(wq_w + kk * 256 + mv * 4);
                const float4 q4 = *(const float4*)(qbase + kk * 4);
                const float wa[4] = {w4.x, w4.y, w4.z, w4.w};
                const float qa[4] = {q4.x, q4.y, q4.z, q4.w};
#pragma unroll
                for (int m = 0; m < 4; ++m)
#pragma unroll
                    for (int r = 0; r < 4; ++r)
                        a[m][r] = fmaf(wa[m], qa[r], a[m][r]);
            }
#pragma unroll
            for (int m = 0; m < 4; ++m)
                *(float4*)wqp[kgq][mv * 4 + m] = make_float4(a[m][0], a[m][1], a[m][2], a[m][3]);
        }
        __syncthreads();
        if (tid < 256) {
            float4 s = *(const float4*)wqp[0][tid];
#pragma unroll
            for (int g = 1; g < 8; ++g) {
                const float4 p = *(const float4*)wqp[g][tid];
                s.x += p.x; s.y += p.y; s.z += p.z; s.w += p.w;
            }
            *(float4*)wqs[tid] = s;
        }
        __syncthreads();
        // ---- temporal scores: vectorized UH2 reads ----
        {
            float a[8];
#pragma unroll
            for (int j = 0; j < 8; ++j) a[j] = 0.0f;
#pragma unroll 4
            for (int uu = 0; uu < 32; ++uu) {
                const int ug = usl * 32 + uu;
                const float wq = wqs[ug][srow];
                const float vv = vds[ug];
                const int4 wv = *(const int4*)(up0 + uu * 128);
                float d[8];
                unp8(wv, d);
#pragma unroll
                for (int j = 0; j < 8; ++j)
                    a[j] = fmaf(tanh_fast(wq + d[j]), vv, a[j]);
            }
            *(float4*)&scp[usl][srow][tv * 8]     = make_float4(a[0], a[1], a[2], a[3]);
            *(float4*)&scp[usl][srow][tv * 8 + 4] = make_float4(a[4], a[5], a[6], a[7]);
        }
        __syncthreads();
        // ---- softmax -> beta (tid<256) ----
        if (tid < 256) {
            const int w = tid >> 6, lane = tid & 63;
            float s0 = 0.0f, s1 = 0.0f;
#pragma unroll
            for (int g = 0; g < 8; ++g) {
                s0 += scp[g][w][lane];
                s1 += scp[g][w][lane + 64];
            }
            float mx = fmaxf(s0, s1);
            for (int o = 32; o > 0; o >>= 1) mx = fmaxf(mx, __shfl_xor(mx, o, 64));
            const float e0 = __expf(s0 - mx), e1 = __expf(s1 - mx);
            float sm = e0 + e1;
            for (int o = 32; o > 0; o >>= 1) sm += __shfl_xor(sm, o, 64);
            const float inv = __fdividef(1.0f, sm);
            beta[lane][w] = e0 * inv;
            beta[lane + 64][w] = e1 * inv;
        }
        __syncthreads();
        // ---- ctx partials: vectorized H reads ----
        {
            float c[8];
#pragma unroll
            for (int j = 0; j < 8; ++j) c[j] = 0.0f;
#pragma unroll 4
            for (int s = 0; s < 32; ++s) {
                const float bt = beta[ssl2 * 32 + s][crow];
                const int4 wv = *(const int4*)(hp0 + s * 256);
                float hv[8];
                unp8(wv, hv);
#pragma unroll
                for (int j = 0; j < 8; ++j)
                    c[j] = fmaf(bt, hv[j], c[j]);
            }
            *(float4*)&ctxp[ssl2][crow][mv8 * 8]     = make_float4(c[0], c[1], c[2], c[3]);
            *(float4*)&ctxp[ssl2][crow][mv8 * 8 + 4] = make_float4(c[4], c[5], c[6], c[7]);
        }
        __syncthreads();
        // ---- ctx combine (tid<256) ----
        if (tid < 256) {
            const int m = tid;
            float cr[4];
#pragma unroll
            for (int r = 0; r < 4; ++r)
                cr[r] = ctxp[0][r][m] + ctxp[1][r][m] + ctxp[2][r][m] + ctxp[3][r][m];
            *(float4*)ctx4[m] = make_float4(cr[0], cr[1], cr[2], cr[3]);
        }
        __syncthreads();
        if (td == 127) break;     // final ctx computed with final (d,s)
        // ---- y_tilde (tid<256) ----
        if (tid < 256) {
            const int w = tid >> 6, lane = tid & 63;
            float s = ctx4[lane][w] * wt1s[lane]
                    + ctx4[lane + 64][w] * wt1s[lane + 64]
                    + ctx4[lane + 128][w] * wt1s[lane + 128]
                    + ctx4[lane + 192][w] * wt1s[lane + 192];
            for (int o = 32; o > 0; o >>= 1) s += __shfl_xor(s, o, 64);
            if (lane == 0)
                yts[w] = s + wt_b[0] + wt_w[0] * dec_data[(long)(b0 + w) * 128 + td];
        }
        __syncthreads();
        // ---- gates: k-split 2 (y+128 / 128) ----
        float acc[4][4];
        if (ks == 0) {
            const float4 wv0 = *(const float4*)gw;
            const float4 y4 = *(const float4*)yts;
            const float wa0[4] = {wv0.x, wv0.y, wv0.z, wv0.w};
            const float ya[4] = {y4.x, y4.y, y4.z, y4.w};
#pragma unroll
            for (int q = 0; q < 4; ++q)
#pragma unroll
                for (int r = 0; r < 4; ++r) acc[q][r] = wa0[q] * ya[r];
            const float* gw2 = gw + 1024;
#pragma unroll 8
            for (int k = 0; k < 128; ++k) {
                const float4 wv = *(const float4*)(gw2 + (long)k * 1024);
                const float4 xv = *(const float4*)ds4[k];
                const float wa[4] = {wv.x, wv.y, wv.z, wv.w};
                const float xa[4] = {xv.x, xv.y, xv.z, xv.w};
#pragma unroll
                for (int q = 0; q < 4; ++q)
#pragma unroll
                    for (int r = 0; r < 4; ++r)
                        acc[q][r] = fmaf(wa[q], xa[r], acc[q][r]);
            }
        } else {
#pragma unroll
            for (int q = 0; q < 4; ++q)
#pragma unroll
                for (int r = 0; r < 4; ++r) acc[q][r] = 0.0f;
            const float* gw2 = gw + 1024 + 128 * 1024;
#pragma unroll 8
            for (int k = 0; k < 128; ++k) {
                const float4 wv = *(const float4*)(gw2 + (long)k * 1024);
                const float4 xv = *(const float4*)ds4[128 + k];
                const float wa[4] = {wv.x, wv.y, wv.z, wv.w};
                const float xa[4] = {xv.x, xv.y, xv.z, xv.w};
#pragma unroll
                for (int q = 0; q < 4; ++q)
#pragma unroll
                    for (int r = 0; r < 4; ++r)
                        acc[q][r] = fmaf(wa[q], xa[r], acc[q][r]);
            }
#pragma unroll
            for (int q = 0; q < 4; ++q)
#pragma unroll
                for (int r = 0; r < 4; ++r) gp[q][r][u] = acc[q][r];
        }
        __syncthreads();
        if (ks == 0) {
#pragma unroll
            for (int r = 0; r < 4; ++r) {
                const float iv = sig_fast(acc[0][r] + gp[0][r][u] + b_i);
                const float fv = sig_fast(acc[1][r] + gp[1][r][u] + b_f);
                const float gv = tanh_fast(acc[2][r] + gp[2][r][u] + b_g);
                const float ov = sig_fast(acc[3][r] + gp[3][r][u] + b_o);
                const float sn = fv * ss4[u][r] + iv * gv;
                const float dn = ov * tanh_fast(sn);
                ss4[u][r] = sn;
                ds4[u][r] = dn;
            }
        }
        __syncthreads();
    }
    // ---- final MLP: l1 k-split 2 (ds / ctx), then l2 wave-reduce ----
    {
        const float* src = l1T + ks * 256 * 256;
        float a0 = 0, a1 = 0, a2 = 0, a3 = 0;
#pragma unroll 4
        for (int k = 0; k < 256; ++k) {
            const float w = src[k * 256 + u];
            const float4 q = (ks == 0) ? *(const float4*)ds4[k]
                                       : *(const float4*)ctx4[k];
            a0 = fmaf(q.x, w, a0); a1 = fmaf(q.y, w, a1);
            a2 = fmaf(q.z, w, a2); a3 = fmaf(q.w, w, a3);
        }
        if (ks == 1) {
            gp[0][0][u] = a0; gp[0][1][u] = a1; gp[0][2][u] = a2; gp[0][3][u] = a3;
        } else {
            gp[1][0][u] = a0; gp[1][1][u] = a1; gp[1][2][u] = a2; gp[1][3][u] = a3;
        }
    }
    __syncthreads();
    if (tid < 256) {
        const float bb = l1_b[tid];
        *(float4*)o14[tid] = make_float4(
            fmaxf(gp[0][0][tid] + gp[1][0][tid] + bb, 0.f),
            fmaxf(gp[0][1][tid] + gp[1][1][tid] + bb, 0.f),
            fmaxf(gp[0][2][tid] + gp[1][2][tid] + bb, 0.f),
            fmaxf(gp[0][3][tid] + gp[1][3][tid] + bb, 0.f));
    }
    __syncthreads();
    if (tid < 256) {
        const int w = tid >> 6, lane = tid & 63;
        float s = o14[lane][w] * l2s[lane]
                + o14[lane + 64][w] * l2s[lane + 64]
                + o14[lane + 128][w] * l2s[lane + 128]
                + o14[lane + 192][w] * l2s[lane + 192];
        for (int o = 32; o > 0; o >>= 1) s += __shfl_xor(s, o, 64);
        if (lane == 0) out[b0 + w] = s + l2_b[0];
    }
}

extern "C" void kernel_launch(void* const* d_in, const int* in_sizes, int n_in,
                              void* d_out, int out_size, void* d_ws, size_t ws_size,
                              hipStream_t stream)
{
    const float* enc_data = (const float*)d_in[0];
    const float* dec_data = (const float*)d_in[1];
    const float* enc_Wih  = (const float*)d_in[2];
    const float* enc_Whh  = (const float*)d_in[3];
    const float* enc_bih  = (const float*)d_in[4];
    const float* enc_bhh  = (const float*)d_in[5];
    const float* We   = (const float*)d_in[6];
    const float* Ue   = (const float*)d_in[7];
    const float* ve   = (const float*)d_in[8];
    const float* Wd   = (const float*)d_in[9];
    const float* Ud   = (const float*)d_in[10];
    const float* vd   = (const float*)d_in[11];
    const float* wt_w = (const float*)d_in[12];
    const float* wt_b = (const float*)d_in[13];
    const float* dec_Wih = (const float*)d_in[14];
    const float* dec_Whh = (const float*)d_in[15];
    const float* dec_bih = (const float*)d_in[16];
    const float* dec_bhh = (const float*)d_in[17];
    const float* l1_w = (const float*)d_in[18];
    const float* l1_b = (const float*)d_in[19];
    const float* l2_w = (const float*)d_in[20];
    const float* l2_b = (const float*)d_in[21];

    // ---- workspace layout (~171 MB) ----
    ushort_t* Dbf  = (ushort_t*)d_ws;                         // 32 MB
    ushort_t* Hbf  = Dbf + (long)BATCH * TT * NN;             // 64 MB
    ushort_t* UHbf = Hbf + (long)BATCH * TT * MM;             // 64 MB
    float* WencT = (float*)(UHbf + (long)BATCH * MM * TT);
    float* WdecT = WencT + 384 * 1024;
    float* WeT   = WdecT + 257 * 1024;
    float* WdT   = WeT + 512 * 128;
    float* l1T   = WdT + 512 * 256;

    prep_encw_k<<<1536, 256, 0, stream>>>(enc_Wih, enc_Whh, WencT);
    prep_decw_k<<<1028, 256, 0, stream>>>(dec_Wih, dec_Whh, WdecT);
    transpose_k<<<(128 * 512 + 255) / 256, 256, 0, stream>>>(We, WeT, 128, 512);
    transpose_k<<<(256 * 512 + 255) / 256, 256, 0, stream>>>(Wd, WdT, 256, 512);
    transpose_k<<<(256 * 512 + 255) / 256, 256, 0, stream>>>(l1_w, l1T, 256, 512);

    // D[b][s][n] = sum_t Ue[s][t] * enc_data[b][t][n]
    gemm_k<false, true, true, false><<<dim3(NN / 64, TT / 64, BATCH), 256, 0, stream>>>(
        Ue, TT, 0, TT,
        nullptr, 0, 0,
        enc_data, NN, (long)TT * NN,
        nullptr, 0,
        nullptr,
        Dbf, NN, (long)TT * NN);

    enc_persist<<<256, 512, 0, stream>>>(enc_data, Dbf, WeT, ve, WencT,
                                         enc_bih, enc_bhh, Hbf);

    // UH2[b][u][t'] = sum_m Ud[u][m] * H[b][t'][m]
    gemm_k<true, false, true, false><<<dim3(TT / 64, MM / 64, BATCH), 256, 0, stream>>>(
        Ud, MM, 0, MM,
        nullptr, 0, 0,
        Hbf, MM, (long)TT * MM,
        nullptr, 0,
        nullptr,
        UHbf, TT, (long)MM * TT);

    dec_persist<<<256, 512, 0, stream>>>(dec_data, UHbf, Hbf, WdT, vd, WdecT,
                                         dec_bih, dec_bhh, wt_w, wt_b,
                                         l1T, l1_b, l2_w, l2_b, (float*)d_out);
}